// Round 8
// baseline (90.486 us; speedup 1.0000x reference)
//
#include <hip/hip_runtime.h>
#include <hip/hip_bf16.h>
#include <math.h>

// B=4, C=384, H=W=Y=X=64, n_head=1, hd=32, P=4096
#define B_   4
#define C_   384
#define HD_  32
#define P_   4096
#define PADP 4356   // 66*66 padded pixel space
#define QSC_ 0.2550889266f   // (1/sqrt(32)) * log2(e), folded into Wq -> exp2 domain

typedef __attribute__((ext_vector_type(4))) float f32x4;
typedef __attribute__((ext_vector_type(8))) short short8;

static __device__ inline unsigned cvt_pk(float lo, float hi) {
    unsigned r;
    asm("v_cvt_pk_bf16_f32 %0, %1, %2" : "=v"(r) : "v"(lo), "v"(hi));
    return r;
}
static __device__ inline float exp2a(float x) {
    float r;
    asm("v_exp_f32 %0, %1" : "=v"(r) : "v"(x));
    return r;
}
static __device__ inline short bf16_bits(float a) {
    __hip_bfloat16 x = __float2bfloat16(a);
    return *reinterpret_cast<short*>(&x);
}

// ---- merged: weight repack + aoT border zero.
__global__ void repack_kernel(const float* __restrict__ Wq,
                              const float* __restrict__ Wkv,
                              const float* __restrict__ Wout,
                              short* __restrict__ Wball,
                              short* __restrict__ Wbc,
                              unsigned* __restrict__ aoT32) {
    int idx = blockIdx.x * 256 + threadIdx.x;
    if (idx < B_ * 260 * 16) {   // zero the 260 border pixels x 16 dwords
        int j = idx & 15;
        int p = (idx >> 4) % 260;
        int b = idx / (260 * 16);
        int hh, ww;
        if (p < 66)       { hh = 0;  ww = p; }
        else if (p < 132) { hh = 65; ww = p - 66; }
        else { int i = p - 132; hh = 1 + (i >> 1); ww = (i & 1) * 65; }
        aoT32[((size_t)b * PADP + hh * 66 + ww) * 16 + j] = 0;
    }
    if (idx < 96 * C_) {
        int r = idx / C_, c = idx % C_;
        float v = (r < 32) ? Wq[r * C_ + c] * QSC_ : Wkv[(r - 32) * C_ + c];
        Wball[idx] = bf16_bits(v);
    }
    int j = idx - 96 * C_;
    if (j >= 0 && j < 9 * 384 * 32) {
        int ci = j & 31;
        int co = (j >> 5) % 384;
        int kk = j / (384 * 32);
        int ky = kk / 3, kx = kk % 3;
        Wbc[j] = bf16_bits(Wout[((co * 32 + ci) * 3 + ky) * 3 + kx]);
    }
}

// ---- unified q/k/v projection from f32 inputs.
__global__ __launch_bounds__(768)
void proj_kernel(const float* __restrict__ x, const float* __restrict__ xe,
                 const short* __restrict__ Wball,
                 short* __restrict__ qT, short* __restrict__ kT,
                 short* __restrict__ vT) {
    int b = blockIdx.y;
    int p0 = blockIdx.x << 5;
    int t = threadIdx.x, w = t >> 6, l = t & 63, lq = l & 15, h = l >> 4;
    int mt = w >> 1, pg = w & 1;
    int p = p0 + pg * 16 + lq;
    const float* in = (mt < 2) ? x : xe;
    const float* xb = in + (size_t)b * C_ * P_ + p;
    const short* Ap = Wball + (size_t)(mt * 16 + lq) * C_ + h * 8;
    f32x4 acc = {0.f, 0.f, 0.f, 0.f};
    for (int ks = 0; ks < 12; ++ks) {
        float xv[8];
        #pragma unroll
        for (int jj = 0; jj < 8; ++jj)
            xv[jj] = xb[(size_t)(ks * 32 + h * 8 + jj) * P_];
        unsigned u[4];
        #pragma unroll
        for (int jj = 0; jj < 4; ++jj) u[jj] = cvt_pk(xv[2 * jj], xv[2 * jj + 1]);
        short8 bf;
        __builtin_memcpy(&bf, u, 16);
        short8 af = *(const short8*)(Ap + ks * 32);
        acc = __builtin_amdgcn_mfma_f32_16x16x32_bf16(af, bf, acc, 0, 0, 0);
    }
    if (mt < 4) {
        short* dst = (mt < 2) ? qT : kT;
        int d = (mt & 1) * 16 + h * 4;
        uint2 u;
        u.x = cvt_pk(acc[0], acc[1]);
        u.y = cvt_pk(acc[2], acc[3]);
        *(uint2*)(dst + ((size_t)b * P_ + p) * HD_ + d) = u;
    } else {
        int d = (mt - 4) * 16 + h * 4;
        #pragma unroll
        for (int r = 0; r < 4; ++r)
            vT[((size_t)b * HD_ + d + r) * P_ + p] = bf16_bits(acc[r]);
    }
}

// ---- Flash attention, MFMA, fixed-max softmax, 32-query tiles.
// grid B_*128 (32-q tiles), 512 thr (8 waves); wave w: keys [w*512, +512) = 8x64-key tiles.
// Cross-wave combine: plain-sum ds_add into shared O (fixed-max => no max state).
__global__ __launch_bounds__(512, 4)
void attn_mfma_kernel(const short* __restrict__ qT,
                      const short* __restrict__ kT,
                      const short* __restrict__ vT,
                      short* __restrict__ aoT) {
    __shared__ unsigned p_lds[8][1024];   // per-wave [32 q][64 keys] bf16, swizzled
    __shared__ float o_sh[32][33];        // [d][q] plain-sum accumulator
    __shared__ float l_sh[32];

    int blk = blockIdx.x;
    int b = blk >> 7;
    int q0 = (blk & 127) << 5;
    int t = threadIdx.x, w = t >> 6, l = t & 63, lq = l & 15, h = l >> 4;

    // zero shared accumulators (o_sh and l_sh zeroed explicitly, no layout assumption)
    for (int i = t; i < 32 * 33; i += 512) ((float*)o_sh)[i] = 0.f;
    if (t < 32) l_sh[t] = 0.f;

    const short* qTb = qT + ((size_t)b * P_ + q0) * HD_;
    const short* kTb = kT + (size_t)b * P_ * HD_;
    const short* vb  = vT + (size_t)b * HD_ * P_;

    short8 qf0 = *(const short8*)(qTb + lq * HD_ + h * 8);
    short8 qf1 = *(const short8*)(qTb + (16 + lq) * HD_ + h * 8);

    f32x4 o00 = {0.f,0.f,0.f,0.f}, o01 = {0.f,0.f,0.f,0.f};
    f32x4 o10 = {0.f,0.f,0.f,0.f}, o11 = {0.f,0.f,0.f,0.f};
    float lsum0 = 0.f, lsum1 = 0.f;
    unsigned* myp = &p_lds[w][0];
    int swz = (lq & 7) << 4;

    int key_base = w * 512;
    short8 kf[4];
    {
        const short* kp = kTb + (size_t)(key_base + lq) * HD_ + h * 8;
        #pragma unroll
        for (int tt = 0; tt < 4; ++tt) kf[tt] = *(const short8*)(kp + tt * 16 * HD_);
    }
    __syncthreads();   // o_sh/l_sh zero visible before any ds_add

    for (int kt = 0; kt < 8; ++kt) {
        int key0 = key_base + kt * 64;
        // V loads for this tile (issue early; consumed after softmax chain)
        const short* vp = vb + (size_t)lq * P_ + key0 + h * 8;
        short8 vf0 = *(const short8*)(vp);
        short8 vf1 = *(const short8*)(vp + 32);
        short8 vf2 = *(const short8*)(vp + 16 * P_);
        short8 vf3 = *(const short8*)(vp + 16 * P_ + 32);

        // QK^T: 8 MFMAs (4 key-frags x 2 q-tiles)
        f32x4 st0[4], st1[4];
        __builtin_amdgcn_s_setprio(1);
        #pragma unroll
        for (int tt = 0; tt < 4; ++tt) {
            st0[tt] = __builtin_amdgcn_mfma_f32_16x16x32_bf16(kf[tt], qf0,
                          (f32x4){0.f,0.f,0.f,0.f}, 0, 0, 0);
            st1[tt] = __builtin_amdgcn_mfma_f32_16x16x32_bf16(kf[tt], qf1,
                          (f32x4){0.f,0.f,0.f,0.f}, 0, 0, 0);
        }
        __builtin_amdgcn_s_setprio(0);

        // prefetch next K tile
        if (kt < 7) {
            const short* kp = kTb + (size_t)(key0 + 64 + lq) * HD_ + h * 8;
            #pragma unroll
            for (int tt = 0; tt < 4; ++tt) kf[tt] = *(const short8*)(kp + tt * 16 * HD_);
        }

        // fixed-max softmax (exp2 domain), q-tile 0 then 1
        #pragma unroll
        for (int qt = 0; qt < 2; ++qt) {
            f32x4* st = qt ? st1 : st0;
            float e[16];
            #pragma unroll
            for (int tt = 0; tt < 4; ++tt)
                #pragma unroll
                for (int r = 0; r < 4; ++r) e[tt * 4 + r] = exp2a(st[tt][r]);
            float ls = 0.f;
            #pragma unroll
            for (int i = 0; i < 16; i += 4)
                ls += (e[i] + e[i + 1]) + (e[i + 2] + e[i + 3]);
            if (qt) lsum1 += ls; else lsum0 += ls;
            unsigned* row = myp + ((qt * 16 + lq) * 128 >> 2);
            #pragma unroll
            for (int tt = 0; tt < 4; ++tt) {
                int u0 = tt * 32 + h * 8;
                row[((u0 + 0) ^ swz) >> 2] = cvt_pk(e[tt * 4 + 0], e[tt * 4 + 1]);
                row[((u0 + 4) ^ swz) >> 2] = cvt_pk(e[tt * 4 + 2], e[tt * 4 + 3]);
            }
        }

        // PV: 8 MFMAs (2 d-tiles x 2 q-tiles x 2 key-halves)
        short8 pb00, pb01, pb10, pb11;   // pb[qt][half]
        __builtin_memcpy(&pb00, (const char*)myp + lq * 128        + ((h * 16 + 0)  ^ swz), 16);
        __builtin_memcpy(&pb01, (const char*)myp + lq * 128        + ((h * 16 + 64) ^ swz), 16);
        __builtin_memcpy(&pb10, (const char*)myp + (16 + lq) * 128 + ((h * 16 + 0)  ^ swz), 16);
        __builtin_memcpy(&pb11, (const char*)myp + (16 + lq) * 128 + ((h * 16 + 64) ^ swz), 16);

        __builtin_amdgcn_s_setprio(1);
        o00 = __builtin_amdgcn_mfma_f32_16x16x32_bf16(vf0, pb00, o00, 0, 0, 0);
        o00 = __builtin_amdgcn_mfma_f32_16x16x32_bf16(vf1, pb01, o00, 0, 0, 0);
        o01 = __builtin_amdgcn_mfma_f32_16x16x32_bf16(vf0, pb10, o01, 0, 0, 0);
        o01 = __builtin_amdgcn_mfma_f32_16x16x32_bf16(vf1, pb11, o01, 0, 0, 0);
        o10 = __builtin_amdgcn_mfma_f32_16x16x32_bf16(vf2, pb00, o10, 0, 0, 0);
        o10 = __builtin_amdgcn_mfma_f32_16x16x32_bf16(vf3, pb01, o10, 0, 0, 0);
        o11 = __builtin_amdgcn_mfma_f32_16x16x32_bf16(vf2, pb10, o11, 0, 0, 0);
        o11 = __builtin_amdgcn_mfma_f32_16x16x32_bf16(vf3, pb11, o11, 0, 0, 0);
        __builtin_amdgcn_s_setprio(0);
    }

    // cross-lane l reduction (per q)
    lsum0 += __shfl_xor(lsum0, 16); lsum0 += __shfl_xor(lsum0, 32);
    lsum1 += __shfl_xor(lsum1, 16); lsum1 += __shfl_xor(lsum1, 32);

    // plain-sum combine into shared accumulators
    #pragma unroll
    for (int r = 0; r < 4; ++r) {
        atomicAdd(&o_sh[h * 4 + r][lq],           o00[r]);
        atomicAdd(&o_sh[h * 4 + r][16 + lq],      o01[r]);
        atomicAdd(&o_sh[16 + h * 4 + r][lq],      o10[r]);
        atomicAdd(&o_sh[16 + h * 4 + r][16 + lq], o11[r]);
    }
    if (h == 0) {
        atomicAdd(&l_sh[lq],      lsum0);
        atomicAdd(&l_sh[16 + lq], lsum1);
    }
    __syncthreads();

    // final normalize + write: 512 pair-writes = 32 q x 16 d-pairs, ONE per thread
    {
        int qq = t >> 4;            // 0..31
        int d0 = (t & 15) * 2;      // 0..30
        float inv = 1.f / l_sh[qq];
        float v0 = o_sh[d0][qq], v1 = o_sh[d0 + 1][qq];
        int p = q0 + qq;
        int hh = p >> 6, ww2 = p & 63;
        unsigned* dst = (unsigned*)(aoT +
            ((size_t)b * PADP + (hh + 1) * 66 + (ww2 + 1)) * HD_ + d0);
        *dst = cvt_pk(v0 * inv, v1 * inv);
    }
}

// ---- Conv implicit GEMM: 512 threads (8 waves), wave w: co [w*48, w*48+48), 32-pixel tile
__global__ __launch_bounds__(512)
void conv_mfma_kernel(const short* __restrict__ Wbc,
                      const short* __restrict__ aoT,
                      const float* __restrict__ bout,
                      const float* __restrict__ x,
                      float* __restrict__ out) {
    int blk = blockIdx.x;
    int b = blk >> 7;
    int p0 = (blk & 127) << 5;
    int t = threadIdx.x;
    int w = t >> 6, l = t & 63, lq = l & 15, h = l >> 4;
    int co0 = w * 48;

    const short* aob = aoT + (size_t)b * PADP * HD_;
    const short* bptr[2];
    #pragma unroll
    for (int n = 0; n < 2; ++n) {
        int p = p0 + n * 16 + lq;
        int hh = p >> 6, ww = p & 63;
        bptr[n] = aob + (size_t)(hh * 66 + ww) * HD_ + h * 8;
    }
    const short* aptr = Wbc + (size_t)(co0 + lq) * 32 + h * 8;

    f32x4 acc[3][2];
    #pragma unroll
    for (int m = 0; m < 3; ++m)
        #pragma unroll
        for (int n = 0; n < 2; ++n) acc[m][n] = (f32x4){0.f, 0.f, 0.f, 0.f};

    short8 Bf0 = *(const short8*)(bptr[0]);
    short8 Bf1 = *(const short8*)(bptr[1]);
    #pragma unroll
    for (int kk = 0; kk < 9; ++kk) {
        short8 nB0, nB1;
        if (kk < 8) {
            int ky = (kk + 1) / 3, kx = (kk + 1) % 3;
            nB0 = *(const short8*)(bptr[0] + (ky * 66 + kx) * HD_);
            nB1 = *(const short8*)(bptr[1] + (ky * 66 + kx) * HD_);
        } else { nB0 = Bf0; nB1 = Bf1; }
        #pragma unroll
        for (int m = 0; m < 3; ++m) {
            short8 Af = *(const short8*)(aptr + kk * 12288 + m * 512);
            acc[m][0] = __builtin_amdgcn_mfma_f32_16x16x32_bf16(Af, Bf0, acc[m][0], 0, 0, 0);
            acc[m][1] = __builtin_amdgcn_mfma_f32_16x16x32_bf16(Af, Bf1, acc[m][1], 0, 0, 0);
        }
        Bf0 = nB0; Bf1 = nB1;
    }

    #pragma unroll
    for (int m = 0; m < 3; ++m) {
        #pragma unroll
        for (int r = 0; r < 4; ++r) {
            int co = co0 + m * 16 + h * 4 + r;
            float bias = bout[co];
            #pragma unroll
            for (int n = 0; n < 2; ++n) {
                int p = p0 + n * 16 + lq;
                size_t idx = ((size_t)b * C_ + co) * P_ + p;
                out[idx] = acc[m][n][r] + bias + x[idx];
            }
        }
    }
}

extern "C" void kernel_launch(void* const* d_in, const int* in_sizes, int n_in,
                              void* d_out, int out_size, void* d_ws, size_t ws_size,
                              hipStream_t stream) {
    const float* x    = (const float*)d_in[0];
    const float* xe   = (const float*)d_in[1];
    const float* Wq   = (const float*)d_in[2];
    const float* Wkv  = (const float*)d_in[3];
    const float* Wout = (const float*)d_in[4];
    const float* bout = (const float*)d_in[5];
    float* out = (float*)d_out;

    short* qT    = (short*)d_ws;                      // B*P*32
    short* kT    = qT  + (size_t)B_ * P_ * HD_;       // B*P*32
    short* vT    = kT  + (size_t)B_ * P_ * HD_;       // B*32*P
    short* aoT   = vT  + (size_t)B_ * P_ * HD_;       // B*PADP*32
    short* Wball = aoT + (size_t)B_ * PADP * HD_;     // 96*384
    short* Wbc   = Wball + 96 * C_;                   // 9*384*32

    repack_kernel<<<576, 256, 0, stream>>>(Wq, Wkv, Wout, Wball, Wbc, (unsigned*)aoT);
    proj_kernel<<<dim3(128, B_), 768, 0, stream>>>(x, xe, Wball, qT, kT, vT);
    attn_mfma_kernel<<<B_ * 128, 512, 0, stream>>>(qT, kT, vT, aoT);
    conv_mfma_kernel<<<B_ * 128, 512, 0, stream>>>(Wbc, aoT, bout, x, out);
}